// Round 2
// baseline (408.472 us; speedup 1.0000x reference)
//
#include <hip/hip_runtime.h>
#include <math.h>

#define B_ 16
#define W_ 2048
#define C_ 512

// ---------------- workspace layout (bytes) ----------------
// Xb  (bf16) [B,W,C]  @ 0          (33554432 B)
// Bt  (bf16) [B,C,C]  @ 33554432   ( 8388608 B)   Bt[b][j][i] = relu(adj[b][i][j])/indeg[b][j]
// Xsp (bf16) [B,W,C]  @ 41943040   (33554432 B)
// tt    f32  [B,W]    @ 75497472   (  131072 B)   (raw row sums; 1/C folded at consumer)
#define OFF_XB    0
#define OFF_BT    33554432
#define OFF_XSP   41943040
#define OFF_TT    75497472

typedef short v8s __attribute__((ext_vector_type(8)));
typedef float v4f __attribute__((ext_vector_type(4)));
typedef float v2f __attribute__((ext_vector_type(2)));
typedef unsigned int u32;

__device__ __forceinline__ float softplusf(float x) {
    return fmaxf(x, 0.f) + log1pf(expf(-fabsf(x)));
}
// fast softplus: native v_exp_f32 / v_log_f32 (error ~1e-7 abs, tolerance is 3.9e-3)
__device__ __forceinline__ float softplus_fast(float x) {
    return fmaxf(x, 0.f) + __logf(1.f + __expf(-fabsf(x)));
}
__device__ __forceinline__ unsigned short f2bf(float x) {
    unsigned int u = __float_as_uint(x);
    unsigned int r = (u + 0x7FFFu + ((u >> 16) & 1u)) >> 16;   // RNE
    return (unsigned short)r;
}
__device__ __forceinline__ float bf2f(unsigned int h) {
    return __uint_as_float(h << 16);
}
// async global->LDS, 16B per lane; LDS dest must be wave-uniform base + lane*16
__device__ __forceinline__ void gload16(const ushort* g, ushort* l) {
    __builtin_amdgcn_global_load_lds(
        (const __attribute__((address_space(1))) u32*)(g),
        (__attribute__((address_space(3))) u32*)(l), 16, 0, 0);
}

// ---- kernel 1: fused in-degree + relu/normalize/transpose bf16 ----
__global__ __launch_bounds__(256) void prep_adj(const float* __restrict__ adj,
                                                ushort* __restrict__ Bt) {
    __shared__ float cs[8][32];
    __shared__ float inv[32];
    __shared__ float t[32][33];
    const int b = blockIdx.y, j0 = blockIdx.x * 32;
    const int tx = threadIdx.x & 31, ty = threadIdx.x >> 5;   // ty 0..7
    const float* src = adj + (size_t)b * C_ * C_;

    float s = 0.f;
#pragma unroll 4
    for (int it = 0; it < C_ / 8; it++)
        s += fmaxf(src[(size_t)(it * 8 + ty) * C_ + j0 + tx], 0.f);
    cs[ty][tx] = s;
    __syncthreads();
    if (ty == 0) {
        float tot = cs[0][tx] + cs[1][tx] + cs[2][tx] + cs[3][tx]
                  + cs[4][tx] + cs[5][tx] + cs[6][tx] + cs[7][tx];
        inv[tx] = 1.f / fmaxf(tot, 1e-4f);
    }

    const int jr = threadIdx.x >> 4;          // 0..15
    const int ic = (threadIdx.x & 15) * 2;
    for (int i0t = 0; i0t < C_; i0t += 32) {
        __syncthreads();
#pragma unroll
        for (int rr = 0; rr < 4; rr++) {
            int ii = ty + rr * 8;
            t[ii][tx] = fmaxf(src[(size_t)(i0t + ii) * C_ + j0 + tx], 0.f);
        }
        __syncthreads();
#pragma unroll
        for (int pp = 0; pp < 2; pp++) {
            int j = jr + pp * 16;
            float iv = inv[j];
            ushort2 o;
            o.x = f2bf(t[ic][j] * iv);
            o.y = f2bf(t[ic + 1][j] * iv);
            *(ushort2*)&Bt[(size_t)b * C_ * C_ + (size_t)(j0 + j) * C_ + i0t + ic] = o;
        }
    }
}

// ---- kernel 2: X_sfr fp32 -> bf16 ----
__global__ void convertA(const float* __restrict__ X, ushort* __restrict__ Xb) {
    int idx = blockIdx.x * 256 + threadIdx.x;      // 4 elems per thread
    float4 v = ((const float4*)X)[idx];
    ushort4 o;
    o.x = f2bf(v.x); o.y = f2bf(v.y); o.z = f2bf(v.z); o.w = f2bf(v.w);
    ((ushort4*)Xb)[idx] = o;
}

// ---- kernel 3: MFMA GEMM (m97 structure) + fused tt row-sum epilogue ----
__global__ __launch_bounds__(256) void gemm_mfma(const ushort* __restrict__ Xb,
                                                 const ushort* __restrict__ Bt,
                                                 ushort* __restrict__ Xsp,
                                                 float* __restrict__ tt) {
    __shared__ ushort As[128 * 32];
    __shared__ ushort Bs[128 * 32];
    const int b  = blockIdx.z;
    const int m0 = blockIdx.y * 128;
    const int n0 = blockIdx.x * 128;
    const int tid  = threadIdx.x;
    const int wave = tid >> 6, lane = tid & 63;
    const int quad = lane >> 4, l16 = lane & 15;
    const int mw = (wave & 1) * 64, nw = (wave >> 1) * 64;

    const ushort* Ag = Xb + (size_t)b * W_ * C_ + (size_t)m0 * C_;
    const ushort* Bg = Bt + (size_t)b * C_ * C_ + (size_t)n0 * C_;

    const int sm = tid >> 2;
    const int sk = (tid & 3) * 8;

    v4f acc[4][4];
#pragma unroll
    for (int mt = 0; mt < 4; mt++)
#pragma unroll
        for (int nt = 0; nt < 4; nt++)
            acc[mt][nt] = (v4f){0.f, 0.f, 0.f, 0.f};

    for (int k0 = 0; k0 < C_; k0 += 32) {
        __syncthreads();
        gload16(Ag + (size_t)sm * C_ + k0 + sk,        As + tid * 8);
        gload16(Ag + (size_t)(sm + 64) * C_ + k0 + sk, As + 2048 + tid * 8);
        gload16(Bg + (size_t)sm * C_ + k0 + sk,        Bs + tid * 8);
        gload16(Bg + (size_t)(sm + 64) * C_ + k0 + sk, Bs + 2048 + tid * 8);
        __syncthreads();

        v8s af[4], bf[4];
#pragma unroll
        for (int mt = 0; mt < 4; mt++)
            af[mt] = *(const v8s*)&As[(mw + mt * 16 + l16) * 32 + quad * 8];
#pragma unroll
        for (int nt = 0; nt < 4; nt++)
            bf[nt] = *(const v8s*)&Bs[(nw + nt * 16 + l16) * 32 + quad * 8];
#pragma unroll
        for (int mt = 0; mt < 4; mt++)
#pragma unroll
            for (int nt = 0; nt < 4; nt++)
                acc[mt][nt] = __builtin_amdgcn_mfma_f32_16x16x32_bf16(af[mt], bf[nt], acc[mt][nt], 0, 0, 0);
    }

#pragma unroll
    for (int mt = 0; mt < 4; mt++) {
#pragma unroll
        for (int nt = 0; nt < 4; nt++) {
            int col = n0 + nw + nt * 16 + l16;
#pragma unroll
            for (int r = 0; r < 4; r++) {
                int row = m0 + mw + mt * 16 + quad * 4 + r;
                Xsp[((size_t)b * W_ + row) * C_ + col] = f2bf(acc[mt][nt][r]);
            }
        }
    }

#pragma unroll
    for (int mt = 0; mt < 4; mt++) {
#pragma unroll
        for (int r = 0; r < 4; r++) {
            float s = acc[mt][0][r] + acc[mt][1][r] + acc[mt][2][r] + acc[mt][3][r];
            s += __shfl_xor(s, 1);
            s += __shfl_xor(s, 2);
            s += __shfl_xor(s, 4);
            s += __shfl_xor(s, 8);
            if (l16 == 0) {
                int row = m0 + mw + mt * 16 + quad * 4 + r;
                atomicAdd(&tt[b * W_ + row], s);
            }
        }
    }
}

// ---- kernel 4: fused band-softmax + temporal aggregation + epilogue ----
// 4 rows per wave (16 rows/block): union of 4 rows' bands = 2*(ns+3) slots,
// each row j loaded once and packed-FMA'd into 4 row accumulators.
// Weights stored as [wave][slot][row] so one ds_read_b128 broadcast fetches
// all 4 row-weights per slot. S == 1/(1+1e-6) analytically (masked softmax
// terms underflow to exactly 0 in the reference as well).
__global__ __launch_bounds__(256) void final_kernel(const ushort* __restrict__ Xsp,
                                                    const float* __restrict__ tt,
                                                    const float* __restrict__ ltp,
                                                    const float* __restrict__ wqp, const float* __restrict__ bqp,
                                                    const float* __restrict__ wkp, const float* __restrict__ bkp,
                                                    const float* __restrict__ wvp, const float* __restrict__ bvp,
                                                    const float* __restrict__ wmup, const float* __restrict__ bmup,
                                                    const float* __restrict__ wsigp, const float* __restrict__ bsigp,
                                                    const int* __restrict__ k1p, const int* __restrict__ k2p,
                                                    float* __restrict__ out) {
    __shared__ float wlds[4][40][4];   // [wave][union slot][row-in-wave]
    const int wid = threadIdx.x >> 6, lane = threadIdx.x & 63;
    // bijective XCD-chunk swizzle: 2048 blocks % 8 == 0, chunk = 256
    const int bid = ((int)blockIdx.x & 7) * 256 + ((int)blockIdx.x >> 3);
    const int i0w = bid * 16 + wid * 4;           // global row base of this wave
    const int b = i0w >> 11, ib = i0w & (W_ - 1);
    const int K1 = k1p[0], K2 = k2p[0];
    int ns = K2 - K1 + 1;
    if (ns > 16) ns = 16;
    const int n2 = 2 * ns;
    const int nsL = ns + 3;            // union segment length
    const int nu = 2 * nsL;
    const float Sc = 1.f / (1.f + 1e-6f);

    for (int k = threadIdx.x; k < 4 * 40 * 4; k += 256) ((float*)wlds)[k] = 0.f;
    __syncthreads();

    {
        // both wave halves active: lanes [0,32) do row rr*2, lanes [32,64) row rr*2+1
        const float cinv = 1.f / C_;
        const float temp = softplus_fast(ltp[0]) + 1e-4f;
        const float invt = 1.f / temp;
        const float wkc = wkp[0] * cinv, bk = bkp[0];
        const float wqc = wqp[0] * cinv, bq = bqp[0];
        const float* ttb = tt + b * W_;
        const int half = lane >> 5;
        const int s = lane & 31;
#pragma unroll
        for (int rr = 0; rr < 2; rr++) {
            const int r = rr * 2 + half;
            const int i = ib + r;
            const float q = wqc * ttb[i] + bq;
            int j = (s < ns) ? (i - K2 + s) : (i + K1 + (s - ns));
            bool valid = (s < n2) && (j >= 0) && (j < W_);
            int jc = min(max(j, 0), W_ - 1);
            float l = valid ? (q * (wkc * ttb[jc] + bk) * invt) : -1e30f;
            float mx = l;
#pragma unroll
            for (int off = 16; off > 0; off >>= 1) mx = fmaxf(mx, __shfl_xor(mx, off, 32));
            float e = valid ? __expf(l - mx) : 0.f;
            float T = e;
#pragma unroll
            for (int off = 16; off > 0; off >>= 1) T += __shfl_xor(T, off, 32);
            float wsc = (1.f / T) * Sc;          // p/(S+1e-6), S = sum(p) = 1
            if (valid) {
                int u = (s < ns) ? (r + s) : (nsL + r + (s - ns));
                wlds[wid][u][r] = e * wsc;
            }
        }
    }
    __syncthreads();

    const ushort* Xbp = Xsp + (size_t)b * W_ * C_;
    const int c8 = lane * 8;
    v2f acc2[4][4];                    // 4 rows x 8 channels as float2 pairs
#pragma unroll
    for (int r = 0; r < 4; r++)
#pragma unroll
        for (int p = 0; p < 4; p++) acc2[r][p] = (v2f){0.f, 0.f};

#pragma unroll 4
    for (int u = 0; u < nu; u++) {
        int j = (u < nsL) ? (ib - K2 + u) : (ib + K1 + (u - nsL));
        j = min(max(j, 0), W_ - 1);
        uint4 v = *(const uint4*)(Xbp + (size_t)j * C_ + c8);
        v2f x[4];
        x[0] = (v2f){bf2f(v.x & 0xffffu), bf2f(v.x >> 16)};
        x[1] = (v2f){bf2f(v.y & 0xffffu), bf2f(v.y >> 16)};
        x[2] = (v2f){bf2f(v.z & 0xffffu), bf2f(v.z >> 16)};
        x[3] = (v2f){bf2f(v.w & 0xffffu), bf2f(v.w >> 16)};
        const v4f w4 = *(const v4f*)&wlds[wid][u][0];   // broadcast, all 4 row-weights
#pragma unroll
        for (int r = 0; r < 4; r++) {
            v2f w2 = (v2f){w4[r], w4[r]};
#pragma unroll
            for (int p = 0; p < 4; p++) acc2[r][p] += w2 * x[p];
        }
    }

    const float wv = wvp[0], bvS = bvp[0] * Sc;
    const float wmu = wmup[0], bmu = bmup[0];
    const float wsig = wsigp[0], bsig = bsigp[0];
    const size_t N = (size_t)B_ * W_ * C_;

#pragma unroll
    for (int r = 0; r < 4; r++) {
        uint4 xv = *(const uint4*)(Xbp + (size_t)(ib + r) * C_ + c8);
        float xs[8];
        xs[0] = bf2f(xv.x & 0xffffu); xs[1] = bf2f(xv.x >> 16);
        xs[2] = bf2f(xv.y & 0xffffu); xs[3] = bf2f(xv.y >> 16);
        xs[4] = bf2f(xv.z & 0xffffu); xs[5] = bf2f(xv.z >> 16);
        xs[6] = bf2f(xv.w & 0xffffu); xs[7] = bf2f(xv.w >> 16);

        float mu[8], sg[8];
#pragma unroll
        for (int k = 0; k < 8; k++) {
            float a = acc2[r][k >> 1][k & 1];
            float xf = fmaf(wv, a, bvS) + xs[k];
            mu[k] = fminf(fmaxf(fmaf(wmu, xf, bmu), -20.f), 20.f);
            sg[k] = softplus_fast(fmaf(wsig, xf, bsig)) + 0.1f;
        }

        const size_t base = (size_t)(i0w + r) * C_ + c8;
        __builtin_nontemporal_store((v4f){mu[0], mu[1], mu[2], mu[3]}, (v4f*)&out[base]);
        __builtin_nontemporal_store((v4f){mu[4], mu[5], mu[6], mu[7]}, (v4f*)&out[base + 4]);
        __builtin_nontemporal_store((v4f){sg[0], sg[1], sg[2], sg[3]}, (v4f*)&out[N + base]);
        __builtin_nontemporal_store((v4f){sg[4], sg[5], sg[6], sg[7]}, (v4f*)&out[N + base + 4]);
        __builtin_nontemporal_store((v4f){Sc, Sc, Sc, Sc}, (v4f*)&out[2 * N + base]);
        __builtin_nontemporal_store((v4f){Sc, Sc, Sc, Sc}, (v4f*)&out[2 * N + base + 4]);
    }
}

extern "C" void kernel_launch(void* const* d_in, const int* in_sizes, int n_in,
                              void* d_out, int out_size, void* d_ws, size_t ws_size,
                              hipStream_t stream) {
    const float* X_sfr = (const float*)d_in[0];
    const float* adj   = (const float*)d_in[1];
    const float* ltp   = (const float*)d_in[2];
    const float* wq    = (const float*)d_in[3];
    const float* bq    = (const float*)d_in[4];
    const float* wk    = (const float*)d_in[5];
    const float* bk    = (const float*)d_in[6];
    const float* wv    = (const float*)d_in[7];
    const float* bv    = (const float*)d_in[8];
    const float* wmu   = (const float*)d_in[9];
    const float* bmu   = (const float*)d_in[10];
    const float* wsig  = (const float*)d_in[11];
    const float* bsig  = (const float*)d_in[12];
    const int*   k1p   = (const int*)d_in[13];
    const int*   k2p   = (const int*)d_in[14];

    char* ws = (char*)d_ws;
    ushort* Xb  = (ushort*)(ws + OFF_XB);
    ushort* Bt  = (ushort*)(ws + OFF_BT);
    ushort* Xsp = (ushort*)(ws + OFF_XSP);
    float*  tt  = (float*)(ws + OFF_TT);
    float*  out = (float*)d_out;

    hipMemsetAsync(tt, 0, B_ * W_ * sizeof(float), stream);

    prep_adj<<<dim3(C_ / 32, B_), 256, 0, stream>>>(adj, Bt);

    convertA<<<(B_ * W_ * C_ / 4) / 256, 256, 0, stream>>>(X_sfr, Xb);

    gemm_mfma<<<dim3(C_ / 128, W_ / 128, B_), 256, 0, stream>>>(Xb, Bt, Xsp, tt);

    final_kernel<<<(B_ * W_) / 16, 256, 0, stream>>>(Xsp, tt, ltp, wq, bq, wk, bk,
                                                     wv, bv, wmu, bmu, wsig, bsig,
                                                     k1p, k2p, out);
}

// Round 3
// 406.356 us; speedup vs baseline: 1.0052x; 1.0052x over previous
//
#include <hip/hip_runtime.h>
#include <math.h>

#define B_ 16
#define W_ 2048
#define C_ 512

// ---------------- workspace layout (bytes) ----------------
// Xb  (bf16) [B,W,C]  @ 0          (33554432 B)
// Bt  (bf16) [B,C,C]  @ 33554432   ( 8388608 B)   Bt[b][j][i] = relu(adj[b][i][j])/indeg[b][j]
// Xsp (bf16) [B,W,C]  @ 41943040   (33554432 B)
// tt    f32  [B,W]    @ 75497472   (  131072 B)   (raw row sums; 1/C folded at consumer)
// cs    f32  [B,C]    @ 75628544   (   32768 B)   (adj column sums, atomically accumulated)
#define OFF_XB    0
#define OFF_BT    33554432
#define OFF_XSP   41943040
#define OFF_TT    75497472
#define OFF_CS    75628544

typedef short v8s __attribute__((ext_vector_type(8)));
typedef float v4f __attribute__((ext_vector_type(4)));
typedef float v2f __attribute__((ext_vector_type(2)));
typedef unsigned int u32;

__device__ __forceinline__ float softplus_fast(float x) {
    return fmaxf(x, 0.f) + __logf(1.f + __expf(-fabsf(x)));
}
__device__ __forceinline__ unsigned short f2bf(float x) {
    unsigned int u = __float_as_uint(x);
    unsigned int r = (u + 0x7FFFu + ((u >> 16) & 1u)) >> 16;   // RNE
    return (unsigned short)r;
}
__device__ __forceinline__ float bf2f(unsigned int h) {
    return __uint_as_float(h << 16);
}
// async global->LDS, 16B per lane; LDS dest must be wave-uniform base + lane*16
__device__ __forceinline__ void gload16(const ushort* g, ushort* l) {
    __builtin_amdgcn_global_load_lds(
        (const __attribute__((address_space(1))) u32*)(g),
        (__attribute__((address_space(3))) u32*)(l), 16, 0, 0);
}

// ---- kernel 1a: adj column sums (relu'd), 4 row-partitions per stripe ----
// grid (C/32, 4, B) = 1024 blocks -> 4 blocks/CU.
__global__ __launch_bounds__(256) void colsum_k(const float* __restrict__ adj,
                                                float* __restrict__ cs) {
    __shared__ float red[8][32];
    const int b = blockIdx.z, j0 = blockIdx.x * 32, r0 = blockIdx.y * 128;
    const int tx = threadIdx.x & 31, ty = threadIdx.x >> 5;   // ty 0..7
    const float* src = adj + (size_t)b * C_ * C_;

    float s = 0.f;
#pragma unroll 4
    for (int it = 0; it < 16; it++)
        s += fmaxf(src[(size_t)(r0 + it * 8 + ty) * C_ + j0 + tx], 0.f);
    red[ty][tx] = s;
    __syncthreads();
    if (ty == 0) {
        float tot = red[0][tx] + red[1][tx] + red[2][tx] + red[3][tx]
                  + red[4][tx] + red[5][tx] + red[6][tx] + red[7][tx];
        atomicAdd(&cs[b * C_ + j0 + tx], tot);
    }
}

// ---- kernel 1b: transpose + normalize -> bf16 Bt, 64x64 tiles ----
// grid (C/64, C/64, B) = 1024 blocks -> 4 blocks/CU.
// Bt[b][j][i] = relu(adj[b][i][j]) / max(cs[b][j], 1e-4)
__global__ __launch_bounds__(256) void prep_bt(const float* __restrict__ adj,
                                               const float* __restrict__ cs,
                                               ushort* __restrict__ Bt) {
    __shared__ float t[64][65];
    __shared__ float invs[64];
    const int b = blockIdx.z;
    const int i0 = blockIdx.x * 64;      // adj row / Bt inner dim
    const int j0 = blockIdx.y * 64;      // adj col / Bt row
    const int tid = threadIdx.x;
    const int tx = tid & 15, ty = tid >> 4;   // ty 0..15

    if (tid < 64) invs[tid] = 1.f / fmaxf(cs[b * C_ + j0 + tid], 1e-4f);

#pragma unroll
    for (int p = 0; p < 4; p++) {
        const int iy = ty + p * 16;
        const float4 v = *(const float4*)&adj[((size_t)b * C_ + (i0 + iy)) * C_ + j0 + tx * 4];
        t[iy][tx * 4 + 0] = fmaxf(v.x, 0.f);
        t[iy][tx * 4 + 1] = fmaxf(v.y, 0.f);
        t[iy][tx * 4 + 2] = fmaxf(v.z, 0.f);
        t[iy][tx * 4 + 3] = fmaxf(v.w, 0.f);
    }
    __syncthreads();

    const int jj = tid >> 2;             // 0..63 : Bt row within tile
    const int i4 = (tid & 3) * 16;       // 0,16,32,48 : Bt col chunk
    const float iv = invs[jj];
    v8s o0, o1;
#pragma unroll
    for (int k = 0; k < 8; k++) o0[k] = (short)f2bf(t[i4 + k][jj] * iv);
#pragma unroll
    for (int k = 0; k < 8; k++) o1[k] = (short)f2bf(t[i4 + 8 + k][jj] * iv);
    ushort* dst = &Bt[(size_t)b * C_ * C_ + (size_t)(j0 + jj) * C_ + i0 + i4];
    *(v8s*)dst       = o0;
    *(v8s*)(dst + 8) = o1;
}

// ---- kernel 2: X_sfr fp32 -> bf16 ----
__global__ void convertA(const float* __restrict__ X, ushort* __restrict__ Xb) {
    int idx = blockIdx.x * 256 + threadIdx.x;      // 4 elems per thread
    float4 v = ((const float4*)X)[idx];
    ushort4 o;
    o.x = f2bf(v.x); o.y = f2bf(v.y); o.z = f2bf(v.z); o.w = f2bf(v.w);
    ((ushort4*)Xb)[idx] = o;
}

// ---- kernel 3: MFMA GEMM (m97 structure), swapped operands ----
// mfma(bf, af) computes the transposed tile: lane's 4 acc regs = 4 CONSECUTIVE
// output columns at a fixed output row -> ushort4 packed 8B stores (16 stores
// vs 64 scattered ushort stores). tt row-sum: 2 cross-quad shuffles per mt.
__global__ __launch_bounds__(256) void gemm_mfma(const ushort* __restrict__ Xb,
                                                 const ushort* __restrict__ Bt,
                                                 ushort* __restrict__ Xsp,
                                                 float* __restrict__ tt) {
    __shared__ ushort As[128 * 32];
    __shared__ ushort Bs[128 * 32];
    const int b  = blockIdx.z;
    const int m0 = blockIdx.y * 128;
    const int n0 = blockIdx.x * 128;
    const int tid  = threadIdx.x;
    const int wave = tid >> 6, lane = tid & 63;
    const int quad = lane >> 4, l16 = lane & 15;
    const int mw = (wave & 1) * 64, nw = (wave >> 1) * 64;

    const ushort* Ag = Xb + (size_t)b * W_ * C_ + (size_t)m0 * C_;
    const ushort* Bg = Bt + (size_t)b * C_ * C_ + (size_t)n0 * C_;

    const int sm = tid >> 2;
    const int sk = (tid & 3) * 8;

    v4f acc[4][4];
#pragma unroll
    for (int mt = 0; mt < 4; mt++)
#pragma unroll
        for (int nt = 0; nt < 4; nt++)
            acc[mt][nt] = (v4f){0.f, 0.f, 0.f, 0.f};

    for (int k0 = 0; k0 < C_; k0 += 32) {
        __syncthreads();
        gload16(Ag + (size_t)sm * C_ + k0 + sk,        As + tid * 8);
        gload16(Ag + (size_t)(sm + 64) * C_ + k0 + sk, As + 2048 + tid * 8);
        gload16(Bg + (size_t)sm * C_ + k0 + sk,        Bs + tid * 8);
        gload16(Bg + (size_t)(sm + 64) * C_ + k0 + sk, Bs + 2048 + tid * 8);
        __syncthreads();

        v8s af[4], bf[4];
#pragma unroll
        for (int mt = 0; mt < 4; mt++)
            af[mt] = *(const v8s*)&As[(mw + mt * 16 + l16) * 32 + quad * 8];
#pragma unroll
        for (int nt = 0; nt < 4; nt++)
            bf[nt] = *(const v8s*)&Bs[(nw + nt * 16 + l16) * 32 + quad * 8];
#pragma unroll
        for (int mt = 0; mt < 4; mt++)
#pragma unroll
            for (int nt = 0; nt < 4; nt++)
                acc[mt][nt] = __builtin_amdgcn_mfma_f32_16x16x32_bf16(bf[nt], af[mt], acc[mt][nt], 0, 0, 0);
    }

    // epilogue: transposed C layout -> row = ... + l16, cols = ... + quad*4 + r
#pragma unroll
    for (int mt = 0; mt < 4; mt++) {
        const int row = m0 + mw + mt * 16 + l16;
        ushort* rowp = &Xsp[((size_t)b * W_ + row) * C_];
#pragma unroll
        for (int nt = 0; nt < 4; nt++) {
            const int colb = n0 + nw + nt * 16 + quad * 4;
            ushort4 o;
            o.x = f2bf(acc[mt][nt][0]);
            o.y = f2bf(acc[mt][nt][1]);
            o.z = f2bf(acc[mt][nt][2]);
            o.w = f2bf(acc[mt][nt][3]);
            *(ushort4*)&rowp[colb] = o;
        }
        float s = 0.f;
#pragma unroll
        for (int nt = 0; nt < 4; nt++)
#pragma unroll
            for (int r = 0; r < 4; r++) s += acc[mt][nt][r];
        s += __shfl_xor(s, 16);
        s += __shfl_xor(s, 32);
        if (quad == 0) atomicAdd(&tt[b * W_ + row], s);
    }
}

// ---- kernel 4: fused band-softmax + temporal aggregation + epilogue ----
__global__ __launch_bounds__(256) void final_kernel(const ushort* __restrict__ Xsp,
                                                    const float* __restrict__ tt,
                                                    const float* __restrict__ ltp,
                                                    const float* __restrict__ wqp, const float* __restrict__ bqp,
                                                    const float* __restrict__ wkp, const float* __restrict__ bkp,
                                                    const float* __restrict__ wvp, const float* __restrict__ bvp,
                                                    const float* __restrict__ wmup, const float* __restrict__ bmup,
                                                    const float* __restrict__ wsigp, const float* __restrict__ bsigp,
                                                    const int* __restrict__ k1p, const int* __restrict__ k2p,
                                                    float* __restrict__ out) {
    __shared__ float wlds[4][40][4];   // [wave][union slot][row-in-wave]
    const int wid = threadIdx.x >> 6, lane = threadIdx.x & 63;
    // bijective XCD-chunk swizzle: 2048 blocks % 8 == 0, chunk = 256
    const int bid = ((int)blockIdx.x & 7) * 256 + ((int)blockIdx.x >> 3);
    const int i0w = bid * 16 + wid * 4;           // global row base of this wave
    const int b = i0w >> 11, ib = i0w & (W_ - 1);
    const int K1 = k1p[0], K2 = k2p[0];
    int ns = K2 - K1 + 1;
    if (ns > 16) ns = 16;
    const int n2 = 2 * ns;
    const int nsL = ns + 3;            // union segment length
    const int nu = 2 * nsL;
    const float Sc = 1.f / (1.f + 1e-6f);

    for (int k = threadIdx.x; k < 4 * 40 * 4; k += 256) ((float*)wlds)[k] = 0.f;
    __syncthreads();

    {
        // both wave halves active: lanes [0,32) do row rr*2, lanes [32,64) row rr*2+1
        const float cinv = 1.f / C_;
        const float temp = softplus_fast(ltp[0]) + 1e-4f;
        const float invt = 1.f / temp;
        const float wkc = wkp[0] * cinv, bk = bkp[0];
        const float wqc = wqp[0] * cinv, bq = bqp[0];
        const float* ttb = tt + b * W_;
        const int half = lane >> 5;
        const int s = lane & 31;
#pragma unroll
        for (int rr = 0; rr < 2; rr++) {
            const int r = rr * 2 + half;
            const int i = ib + r;
            const float q = wqc * ttb[i] + bq;
            int j = (s < ns) ? (i - K2 + s) : (i + K1 + (s - ns));
            bool valid = (s < n2) && (j >= 0) && (j < W_);
            int jc = min(max(j, 0), W_ - 1);
            float l = valid ? (q * (wkc * ttb[jc] + bk) * invt) : -1e30f;
            float mx = l;
#pragma unroll
            for (int off = 16; off > 0; off >>= 1) mx = fmaxf(mx, __shfl_xor(mx, off, 32));
            float e = valid ? __expf(l - mx) : 0.f;
            float T = e;
#pragma unroll
            for (int off = 16; off > 0; off >>= 1) T += __shfl_xor(T, off, 32);
            float wsc = (1.f / T) * Sc;          // p/(S+1e-6), S = sum(p) = 1
            if (valid) {
                int u = (s < ns) ? (r + s) : (nsL + r + (s - ns));
                wlds[wid][u][r] = e * wsc;
            }
        }
    }
    __syncthreads();

    const ushort* Xbp = Xsp + (size_t)b * W_ * C_;
    const int c8 = lane * 8;
    v2f acc2[4][4];                    // 4 rows x 8 channels as float2 pairs
#pragma unroll
    for (int r = 0; r < 4; r++)
#pragma unroll
        for (int p = 0; p < 4; p++) acc2[r][p] = (v2f){0.f, 0.f};

#pragma unroll 4
    for (int u = 0; u < nu; u++) {
        int j = (u < nsL) ? (ib - K2 + u) : (ib + K1 + (u - nsL));
        j = min(max(j, 0), W_ - 1);
        uint4 v = *(const uint4*)(Xbp + (size_t)j * C_ + c8);
        v2f x[4];
        x[0] = (v2f){bf2f(v.x & 0xffffu), bf2f(v.x >> 16)};
        x[1] = (v2f){bf2f(v.y & 0xffffu), bf2f(v.y >> 16)};
        x[2] = (v2f){bf2f(v.z & 0xffffu), bf2f(v.z >> 16)};
        x[3] = (v2f){bf2f(v.w & 0xffffu), bf2f(v.w >> 16)};
        const v4f w4 = *(const v4f*)&wlds[wid][u][0];   // broadcast, all 4 row-weights
#pragma unroll
        for (int r = 0; r < 4; r++) {
            v2f w2 = (v2f){w4[r], w4[r]};
#pragma unroll
            for (int p = 0; p < 4; p++) acc2[r][p] += w2 * x[p];
        }
    }

    const float wv = wvp[0], bvS = bvp[0] * Sc;
    const float wmu = wmup[0], bmu = bmup[0];
    const float wsig = wsigp[0], bsig = bsigp[0];
    const size_t N = (size_t)B_ * W_ * C_;

#pragma unroll
    for (int r = 0; r < 4; r++) {
        uint4 xv = *(const uint4*)(Xbp + (size_t)(ib + r) * C_ + c8);
        float xs[8];
        xs[0] = bf2f(xv.x & 0xffffu); xs[1] = bf2f(xv.x >> 16);
        xs[2] = bf2f(xv.y & 0xffffu); xs[3] = bf2f(xv.y >> 16);
        xs[4] = bf2f(xv.z & 0xffffu); xs[5] = bf2f(xv.z >> 16);
        xs[6] = bf2f(xv.w & 0xffffu); xs[7] = bf2f(xv.w >> 16);

        float mu[8], sg[8];
#pragma unroll
        for (int k = 0; k < 8; k++) {
            float a = acc2[r][k >> 1][k & 1];
            float xf = fmaf(wv, a, bvS) + xs[k];
            mu[k] = fminf(fmaxf(fmaf(wmu, xf, bmu), -20.f), 20.f);
            sg[k] = softplus_fast(fmaf(wsig, xf, bsig)) + 0.1f;
        }

        const size_t base = (size_t)(i0w + r) * C_ + c8;
        __builtin_nontemporal_store((v4f){mu[0], mu[1], mu[2], mu[3]}, (v4f*)&out[base]);
        __builtin_nontemporal_store((v4f){mu[4], mu[5], mu[6], mu[7]}, (v4f*)&out[base + 4]);
        __builtin_nontemporal_store((v4f){sg[0], sg[1], sg[2], sg[3]}, (v4f*)&out[N + base]);
        __builtin_nontemporal_store((v4f){sg[4], sg[5], sg[6], sg[7]}, (v4f*)&out[N + base + 4]);
        __builtin_nontemporal_store((v4f){Sc, Sc, Sc, Sc}, (v4f*)&out[2 * N + base]);
        __builtin_nontemporal_store((v4f){Sc, Sc, Sc, Sc}, (v4f*)&out[2 * N + base + 4]);
    }
}

extern "C" void kernel_launch(void* const* d_in, const int* in_sizes, int n_in,
                              void* d_out, int out_size, void* d_ws, size_t ws_size,
                              hipStream_t stream) {
    const float* X_sfr = (const float*)d_in[0];
    const float* adj   = (const float*)d_in[1];
    const float* ltp   = (const float*)d_in[2];
    const float* wq    = (const float*)d_in[3];
    const float* bq    = (const float*)d_in[4];
    const float* wk    = (const float*)d_in[5];
    const float* bk    = (const float*)d_in[6];
    const float* wv    = (const float*)d_in[7];
    const float* bv    = (const float*)d_in[8];
    const float* wmu   = (const float*)d_in[9];
    const float* bmu   = (const float*)d_in[10];
    const float* wsig  = (const float*)d_in[11];
    const float* bsig  = (const float*)d_in[12];
    const int*   k1p   = (const int*)d_in[13];
    const int*   k2p   = (const int*)d_in[14];

    char* ws = (char*)d_ws;
    ushort* Xb  = (ushort*)(ws + OFF_XB);
    ushort* Bt  = (ushort*)(ws + OFF_BT);
    ushort* Xsp = (ushort*)(ws + OFF_XSP);
    float*  tt  = (float*)(ws + OFF_TT);
    float*  cs  = (float*)(ws + OFF_CS);
    float*  out = (float*)d_out;

    // zero tt + cs in one contiguous memset
    hipMemsetAsync(tt, 0, B_ * W_ * sizeof(float) + B_ * C_ * sizeof(float), stream);

    colsum_k<<<dim3(C_ / 32, 4, B_), 256, 0, stream>>>(adj, cs);

    convertA<<<(B_ * W_ * C_ / 4) / 256, 256, 0, stream>>>(X_sfr, Xb);

    prep_bt<<<dim3(C_ / 64, C_ / 64, B_), 256, 0, stream>>>(adj, cs, Bt);

    gemm_mfma<<<dim3(C_ / 128, W_ / 128, B_), 256, 0, stream>>>(Xb, Bt, Xsp, tt);

    final_kernel<<<(B_ * W_) / 16, 256, 0, stream>>>(Xsp, tt, ltp, wq, bq, wk, bk,
                                                     wv, bv, wmu, bmu, wsig, bsig,
                                                     k1p, k2p, out);
}

// Round 4
// 388.058 us; speedup vs baseline: 1.0526x; 1.0472x over previous
//
#include <hip/hip_runtime.h>
#include <math.h>

#define B_ 16
#define W_ 2048
#define C_ 512

// ---------------- workspace layout (bytes) ----------------
// Xb  (bf16) [B,W,C]  @ 0          (33554432 B)
// Bt  (bf16) [B,C,C]  @ 33554432   ( 8388608 B)   Bt[b][j][i] = relu(adj[b][i][j])/indeg[b][j]
// Xsp (bf16) [B,W,C]  @ 41943040   (33554432 B)
// tt    f32  [B,W]    @ 75497472   (  131072 B)   (raw row sums; 1/C folded at consumer)
// cs    f32  [B,C]    @ 75628544   (   32768 B)   (adj column sums, atomically accumulated)
#define OFF_XB    0
#define OFF_BT    33554432
#define OFF_XSP   41943040
#define OFF_TT    75497472
#define OFF_CS    75628544

typedef short v8s __attribute__((ext_vector_type(8)));
typedef float v4f __attribute__((ext_vector_type(4)));
typedef float v2f __attribute__((ext_vector_type(2)));
typedef unsigned int u32;

__device__ __forceinline__ float softplus_fast(float x) {
    return fmaxf(x, 0.f) + __logf(1.f + __expf(-fabsf(x)));
}
__device__ __forceinline__ unsigned short f2bf(float x) {
    unsigned int u = __float_as_uint(x);
    unsigned int r = (u + 0x7FFFu + ((u >> 16) & 1u)) >> 16;   // RNE
    return (unsigned short)r;
}
__device__ __forceinline__ float bf2f_lo(unsigned int u) {     // low bf16 of u32
    return __uint_as_float(u << 16);
}
__device__ __forceinline__ float bf2f_hi(unsigned int u) {     // high bf16 of u32
    return __uint_as_float(u & 0xffff0000u);
}
// async global->LDS, 16B per lane; LDS dest must be wave-uniform base + lane*16
__device__ __forceinline__ void gload16(const ushort* g, ushort* l) {
    __builtin_amdgcn_global_load_lds(
        (const __attribute__((address_space(1))) u32*)(g),
        (__attribute__((address_space(3))) u32*)(l), 16, 0, 0);
}

// ---- kernel 1: merged X convert (bf16) + adj column sums ----
// blocks [0,4096): convert 16 elems/thread.  blocks [4096,5120): colsum partials.
__global__ __launch_bounds__(256) void front_k(const float* __restrict__ X,
                                               ushort* __restrict__ Xb,
                                               const float* __restrict__ adj,
                                               float* __restrict__ cs) {
    const int bid = blockIdx.x;
    if (bid < 4096) {
        const size_t e0 = ((size_t)bid * 256 + threadIdx.x) * 16;
        const float4* Xp = (const float4*)(X + e0);
        float4 a = Xp[0], b = Xp[1], c = Xp[2], d = Xp[3];
        v8s o0, o1;
        o0[0] = (short)f2bf(a.x); o0[1] = (short)f2bf(a.y);
        o0[2] = (short)f2bf(a.z); o0[3] = (short)f2bf(a.w);
        o0[4] = (short)f2bf(b.x); o0[5] = (short)f2bf(b.y);
        o0[6] = (short)f2bf(b.z); o0[7] = (short)f2bf(b.w);
        o1[0] = (short)f2bf(c.x); o1[1] = (short)f2bf(c.y);
        o1[2] = (short)f2bf(c.z); o1[3] = (short)f2bf(c.w);
        o1[4] = (short)f2bf(d.x); o1[5] = (short)f2bf(d.y);
        o1[6] = (short)f2bf(d.z); o1[7] = (short)f2bf(d.w);
        *(v8s*)&Xb[e0]     = o0;
        *(v8s*)&Xb[e0 + 8] = o1;
    } else {
        __shared__ float red[8][32];
        const int cb = bid - 4096;                 // 1024 blocks
        const int b  = cb >> 6;
        const int rem = cb & 63;
        const int j0 = (rem & 15) * 32;
        const int r0 = (rem >> 4) * 128;
        const int tx = threadIdx.x & 31, ty = threadIdx.x >> 5;
        const float* src = adj + (size_t)b * C_ * C_;
        float s = 0.f;
#pragma unroll 4
        for (int it = 0; it < 16; it++)
            s += fmaxf(src[(size_t)(r0 + it * 8 + ty) * C_ + j0 + tx], 0.f);
        red[ty][tx] = s;
        __syncthreads();
        if (ty == 0) {
            float tot = red[0][tx] + red[1][tx] + red[2][tx] + red[3][tx]
                      + red[4][tx] + red[5][tx] + red[6][tx] + red[7][tx];
            atomicAdd(&cs[b * C_ + j0 + tx], tot);
        }
    }
}

// ---- kernel 2: transpose + normalize -> bf16 Bt, 64x64 tiles ----
// Bt[b][j][i] = relu(adj[b][i][j]) / max(cs[b][j], 1e-4)
__global__ __launch_bounds__(256) void prep_bt(const float* __restrict__ adj,
                                               const float* __restrict__ cs,
                                               ushort* __restrict__ Bt) {
    __shared__ float t[64][65];
    __shared__ float invs[64];
    const int b = blockIdx.z;
    const int i0 = blockIdx.x * 64;      // adj row / Bt inner dim
    const int j0 = blockIdx.y * 64;      // adj col / Bt row
    const int tid = threadIdx.x;
    const int tx = tid & 15, ty = tid >> 4;   // ty 0..15

    if (tid < 64) invs[tid] = 1.f / fmaxf(cs[b * C_ + j0 + tid], 1e-4f);

#pragma unroll
    for (int p = 0; p < 4; p++) {
        const int iy = ty + p * 16;
        const float4 v = *(const float4*)&adj[((size_t)b * C_ + (i0 + iy)) * C_ + j0 + tx * 4];
        t[iy][tx * 4 + 0] = fmaxf(v.x, 0.f);
        t[iy][tx * 4 + 1] = fmaxf(v.y, 0.f);
        t[iy][tx * 4 + 2] = fmaxf(v.z, 0.f);
        t[iy][tx * 4 + 3] = fmaxf(v.w, 0.f);
    }
    __syncthreads();

    const int jj = tid >> 2;             // 0..63 : Bt row within tile
    const int i4 = (tid & 3) * 16;       // 0,16,32,48 : Bt col chunk
    const float iv = invs[jj];
    v8s o0, o1;
#pragma unroll
    for (int k = 0; k < 8; k++) o0[k] = (short)f2bf(t[i4 + k][jj] * iv);
#pragma unroll
    for (int k = 0; k < 8; k++) o1[k] = (short)f2bf(t[i4 + 8 + k][jj] * iv);
    ushort* dst = &Bt[(size_t)b * C_ * C_ + (size_t)(j0 + jj) * C_ + i0 + i4];
    *(v8s*)dst       = o0;
    *(v8s*)(dst + 8) = o1;
}

// ---- kernel 3: MFMA GEMM, two K-steps per barrier pair ----
// Two independent [128][32] buffer pairs staged under ONE drain+barrier:
// halves the barrier/vmcnt(0) count, doubles loads-in-flight, keeps the
// 64B LDS row stride (BK=64 in one buffer would be a 16-way bank conflict).
// Swapped operands mfma(bf, af): lane's 4 acc regs = 4 consecutive output
// columns -> ushort4 8B stores.
__global__ __launch_bounds__(256) void gemm_mfma(const ushort* __restrict__ Xb,
                                                 const ushort* __restrict__ Bt,
                                                 ushort* __restrict__ Xsp,
                                                 float* __restrict__ tt) {
    __shared__ ushort As[2][128 * 32];
    __shared__ ushort Bs[2][128 * 32];
    const int b  = blockIdx.z;
    const int m0 = blockIdx.y * 128;
    const int n0 = blockIdx.x * 128;
    const int tid  = threadIdx.x;
    const int wave = tid >> 6, lane = tid & 63;
    const int quad = lane >> 4, l16 = lane & 15;
    const int mw = (wave & 1) * 64, nw = (wave >> 1) * 64;

    const ushort* Ag = Xb + (size_t)b * W_ * C_ + (size_t)m0 * C_;
    const ushort* Bg = Bt + (size_t)b * C_ * C_ + (size_t)n0 * C_;

    const int sm = tid >> 2;
    const int sk = (tid & 3) * 8;

    v4f acc[4][4];
#pragma unroll
    for (int mt = 0; mt < 4; mt++)
#pragma unroll
        for (int nt = 0; nt < 4; nt++)
            acc[mt][nt] = (v4f){0.f, 0.f, 0.f, 0.f};

    for (int k0 = 0; k0 < C_; k0 += 64) {
        __syncthreads();
        gload16(Ag + (size_t)sm * C_ + k0 + sk,             &As[0][tid * 8]);
        gload16(Ag + (size_t)(sm + 64) * C_ + k0 + sk,      &As[0][2048 + tid * 8]);
        gload16(Bg + (size_t)sm * C_ + k0 + sk,             &Bs[0][tid * 8]);
        gload16(Bg + (size_t)(sm + 64) * C_ + k0 + sk,      &Bs[0][2048 + tid * 8]);
        gload16(Ag + (size_t)sm * C_ + k0 + 32 + sk,        &As[1][tid * 8]);
        gload16(Ag + (size_t)(sm + 64) * C_ + k0 + 32 + sk, &As[1][2048 + tid * 8]);
        gload16(Bg + (size_t)sm * C_ + k0 + 32 + sk,        &Bs[1][tid * 8]);
        gload16(Bg + (size_t)(sm + 64) * C_ + k0 + 32 + sk, &Bs[1][2048 + tid * 8]);
        __syncthreads();

#pragma unroll
        for (int h = 0; h < 2; h++) {
            v8s af[4], bf[4];
#pragma unroll
            for (int mt = 0; mt < 4; mt++)
                af[mt] = *(const v8s*)&As[h][(mw + mt * 16 + l16) * 32 + quad * 8];
#pragma unroll
            for (int nt = 0; nt < 4; nt++)
                bf[nt] = *(const v8s*)&Bs[h][(nw + nt * 16 + l16) * 32 + quad * 8];
#pragma unroll
            for (int mt = 0; mt < 4; mt++)
#pragma unroll
                for (int nt = 0; nt < 4; nt++)
                    acc[mt][nt] = __builtin_amdgcn_mfma_f32_16x16x32_bf16(bf[nt], af[mt], acc[mt][nt], 0, 0, 0);
        }
    }

    // epilogue: transposed C layout -> row = ... + l16, cols = ... + quad*4 + r
#pragma unroll
    for (int mt = 0; mt < 4; mt++) {
        const int row = m0 + mw + mt * 16 + l16;
        ushort* rowp = &Xsp[((size_t)b * W_ + row) * C_];
#pragma unroll
        for (int nt = 0; nt < 4; nt++) {
            const int colb = n0 + nw + nt * 16 + quad * 4;
            ushort4 o;
            o.x = f2bf(acc[mt][nt][0]);
            o.y = f2bf(acc[mt][nt][1]);
            o.z = f2bf(acc[mt][nt][2]);
            o.w = f2bf(acc[mt][nt][3]);
            *(ushort4*)&rowp[colb] = o;
        }
        float s = 0.f;
#pragma unroll
        for (int nt = 0; nt < 4; nt++)
#pragma unroll
            for (int r = 0; r < 4; r++) s += acc[mt][nt][r];
        s += __shfl_xor(s, 16);
        s += __shfl_xor(s, 32);
        if (quad == 0) atomicAdd(&tt[b * W_ + row], s);
    }
}

// ---- kernel 4: fused band-softmax + temporal aggregation + epilogue ----
__global__ __launch_bounds__(256) void final_kernel(const ushort* __restrict__ Xsp,
                                                    const float* __restrict__ tt,
                                                    const float* __restrict__ ltp,
                                                    const float* __restrict__ wqp, const float* __restrict__ bqp,
                                                    const float* __restrict__ wkp, const float* __restrict__ bkp,
                                                    const float* __restrict__ wvp, const float* __restrict__ bvp,
                                                    const float* __restrict__ wmup, const float* __restrict__ bmup,
                                                    const float* __restrict__ wsigp, const float* __restrict__ bsigp,
                                                    const int* __restrict__ k1p, const int* __restrict__ k2p,
                                                    float* __restrict__ out) {
    __shared__ float wlds[4][40][4];   // [wave][union slot][row-in-wave]
    const int wid = threadIdx.x >> 6, lane = threadIdx.x & 63;
    // bijective XCD-chunk swizzle: 2048 blocks % 8 == 0, chunk = 256
    const int bid = ((int)blockIdx.x & 7) * 256 + ((int)blockIdx.x >> 3);
    const int i0w = bid * 16 + wid * 4;           // global row base of this wave
    const int b = i0w >> 11, ib = i0w & (W_ - 1);
    const int K1 = k1p[0], K2 = k2p[0];
    int ns = K2 - K1 + 1;
    if (ns > 16) ns = 16;
    const int n2 = 2 * ns;
    const int nsL = ns + 3;            // union segment length
    const int nu = 2 * nsL;            // >= 8 always
    const float Sc = 1.f / (1.f + 1e-6f);

    for (int k = threadIdx.x; k < 4 * 40 * 4; k += 256) ((float*)wlds)[k] = 0.f;
    __syncthreads();

    {
        // both wave halves active: lanes [0,32) do row rr*2, lanes [32,64) row rr*2+1
        const float cinv = 1.f / C_;
        const float temp = softplus_fast(ltp[0]) + 1e-4f;
        const float invt = 1.f / temp;
        const float wkc = wkp[0] * cinv, bk = bkp[0];
        const float wqc = wqp[0] * cinv, bq = bqp[0];
        const float* ttb = tt + b * W_;
        const int half = lane >> 5;
        const int s = lane & 31;
#pragma unroll
        for (int rr = 0; rr < 2; rr++) {
            const int r = rr * 2 + half;
            const int i = ib + r;
            const float q = wqc * ttb[i] + bq;
            int j = (s < ns) ? (i - K2 + s) : (i + K1 + (s - ns));
            bool valid = (s < n2) && (j >= 0) && (j < W_);
            int jc = min(max(j, 0), W_ - 1);
            float l = valid ? (q * (wkc * ttb[jc] + bk) * invt) : -1e30f;
            float mx = l;
#pragma unroll
            for (int off = 16; off > 0; off >>= 1) mx = fmaxf(mx, __shfl_xor(mx, off, 32));
            float e = valid ? __expf(l - mx) : 0.f;
            float T = e;
#pragma unroll
            for (int off = 16; off > 0; off >>= 1) T += __shfl_xor(T, off, 32);
            float wsc = (1.f / T) * Sc;          // p/(S+1e-6), S = sum(p) = 1
            if (valid) {
                int u = (s < ns) ? (r + s) : (nsL + r + (s - ns));
                wlds[wid][u][r] = e * wsc;
            }
        }
    }
    __syncthreads();

    const ushort* Xbp = Xsp + (size_t)b * W_ * C_;
    const int c8 = lane * 8;

    // hoist self-row loads (loop-independent) so their latency hides under the loop
    uint4 xv[4];
#pragma unroll
    for (int r = 0; r < 4; r++)
        xv[r] = *(const uint4*)(Xbp + (size_t)(ib + r) * C_ + c8);

    v2f acc2[4][4];                    // 4 rows x 8 channels as float2 pairs
#pragma unroll
    for (int r = 0; r < 4; r++)
#pragma unroll
        for (int p = 0; p < 4; p++) acc2[r][p] = (v2f){0.f, 0.f};

    // 2-deep software pipeline over band rows
    auto band_addr = [&](int u) -> const uint4* {
        int j = (u < nsL) ? (ib - K2 + u) : (ib + K1 + (u - nsL));
        j = min(max(j, 0), W_ - 1);
        return (const uint4*)(Xbp + (size_t)j * C_ + c8);
    };
    uint4 vA = *band_addr(0);
    uint4 vB = *band_addr(1);
    for (int u = 0; u < nu; u++) {
        uint4 v = vA;
        vA = vB;
        if (u + 2 < nu) vB = *band_addr(u + 2);
        v2f x[4];
        x[0] = (v2f){bf2f_lo(v.x), bf2f_hi(v.x)};
        x[1] = (v2f){bf2f_lo(v.y), bf2f_hi(v.y)};
        x[2] = (v2f){bf2f_lo(v.z), bf2f_hi(v.z)};
        x[3] = (v2f){bf2f_lo(v.w), bf2f_hi(v.w)};
        const v4f w4 = *(const v4f*)&wlds[wid][u][0];   // broadcast, all 4 row-weights
#pragma unroll
        for (int r = 0; r < 4; r++) {
            v2f w2 = (v2f){w4[r], w4[r]};
#pragma unroll
            for (int p = 0; p < 4; p++) acc2[r][p] += w2 * x[p];
        }
    }

    const float wv = wvp[0], bvS = bvp[0] * Sc;
    const float wmu = wmup[0], bmu = bmup[0];
    const float wsig = wsigp[0], bsig = bsigp[0];
    const size_t N = (size_t)B_ * W_ * C_;

#pragma unroll
    for (int r = 0; r < 4; r++) {
        float xs[8];
        xs[0] = bf2f_lo(xv[r].x); xs[1] = bf2f_hi(xv[r].x);
        xs[2] = bf2f_lo(xv[r].y); xs[3] = bf2f_hi(xv[r].y);
        xs[4] = bf2f_lo(xv[r].z); xs[5] = bf2f_hi(xv[r].z);
        xs[6] = bf2f_lo(xv[r].w); xs[7] = bf2f_hi(xv[r].w);

        float mu[8], sg[8];
#pragma unroll
        for (int k = 0; k < 8; k++) {
            float a = acc2[r][k >> 1][k & 1];
            float xf = fmaf(wv, a, bvS) + xs[k];
            mu[k] = fminf(fmaxf(fmaf(wmu, xf, bmu), -20.f), 20.f);
            sg[k] = softplus_fast(fmaf(wsig, xf, bsig)) + 0.1f;
        }

        const size_t base = (size_t)(i0w + r) * C_ + c8;
        __builtin_nontemporal_store((v4f){mu[0], mu[1], mu[2], mu[3]}, (v4f*)&out[base]);
        __builtin_nontemporal_store((v4f){mu[4], mu[5], mu[6], mu[7]}, (v4f*)&out[base + 4]);
        __builtin_nontemporal_store((v4f){sg[0], sg[1], sg[2], sg[3]}, (v4f*)&out[N + base]);
        __builtin_nontemporal_store((v4f){sg[4], sg[5], sg[6], sg[7]}, (v4f*)&out[N + base + 4]);
        __builtin_nontemporal_store((v4f){Sc, Sc, Sc, Sc}, (v4f*)&out[2 * N + base]);
        __builtin_nontemporal_store((v4f){Sc, Sc, Sc, Sc}, (v4f*)&out[2 * N + base + 4]);
    }
}

extern "C" void kernel_launch(void* const* d_in, const int* in_sizes, int n_in,
                              void* d_out, int out_size, void* d_ws, size_t ws_size,
                              hipStream_t stream) {
    const float* X_sfr = (const float*)d_in[0];
    const float* adj   = (const float*)d_in[1];
    const float* ltp   = (const float*)d_in[2];
    const float* wq    = (const float*)d_in[3];
    const float* bq    = (const float*)d_in[4];
    const float* wk    = (const float*)d_in[5];
    const float* bk    = (const float*)d_in[6];
    const float* wv    = (const float*)d_in[7];
    const float* bv    = (const float*)d_in[8];
    const float* wmu   = (const float*)d_in[9];
    const float* bmu   = (const float*)d_in[10];
    const float* wsig  = (const float*)d_in[11];
    const float* bsig  = (const float*)d_in[12];
    const int*   k1p   = (const int*)d_in[13];
    const int*   k2p   = (const int*)d_in[14];

    char* ws = (char*)d_ws;
    ushort* Xb  = (ushort*)(ws + OFF_XB);
    ushort* Bt  = (ushort*)(ws + OFF_BT);
    ushort* Xsp = (ushort*)(ws + OFF_XSP);
    float*  tt  = (float*)(ws + OFF_TT);
    float*  cs  = (float*)(ws + OFF_CS);
    float*  out = (float*)d_out;

    // zero tt + cs in one contiguous memset
    hipMemsetAsync(tt, 0, B_ * W_ * sizeof(float) + B_ * C_ * sizeof(float), stream);

    front_k<<<4096 + 1024, 256, 0, stream>>>(X_sfr, Xb, adj, cs);

    prep_bt<<<dim3(C_ / 64, C_ / 64, B_), 256, 0, stream>>>(adj, cs, Bt);

    gemm_mfma<<<dim3(C_ / 128, W_ / 128, B_), 256, 0, stream>>>(Xb, Bt, Xsp, tt);

    final_kernel<<<(B_ * W_) / 16, 256, 0, stream>>>(Xsp, tt, ltp, wq, bq, wk, bk,
                                                     wv, bv, wmu, bmu, wsig, bsig,
                                                     k1p, k2p, out);
}